// Round 1
// baseline (1595.527 us; speedup 1.0000x reference)
//
#include <hip/hip_runtime.h>
#include <hip/hip_bf16.h>
#include <math.h>

#define B_  8
#define N_  1024
#define H_  512
#define NH_ 8
#define HD_ 64

// ---------------------------------------------------------------------------
// GEMM: C[M,Ncols] = X[M,K] @ W[Ncols,K]^T + bias[Ncols]
// (torch Linear layout: W rows are output features; both X and W are
// K-contiguous so tile loads are coalesced float4.)
// Block 256 threads, 64x64 output tile, K-step 16, 4x4 micro-tile/thread.
// ---------------------------------------------------------------------------
__global__ __launch_bounds__(256) void gemm_xwt(
    const float* __restrict__ X, const float* __restrict__ W,
    const float* __restrict__ bias, float* __restrict__ C,
    int M, int Ncols, int K)
{
    __shared__ float Xs[64][17];
    __shared__ float Ws[64][17];

    const int t   = threadIdx.x;
    const int tx  = t & 15;        // col group
    const int ty  = t >> 4;        // row group
    const int row0 = blockIdx.y * 64;
    const int col0 = blockIdx.x * 64;
    const int lrow = t >> 2;       // 0..63  (tile row to load)
    const int lk   = (t & 3) * 4;  // 0,4,8,12 (k offset, float4)

    float c[4][4];
    #pragma unroll
    for (int i = 0; i < 4; ++i)
        #pragma unroll
        for (int j = 0; j < 4; ++j) c[i][j] = 0.f;

    for (int k0 = 0; k0 < K; k0 += 16) {
        __syncthreads();   // previous compute done reading Xs/Ws
        {
            const float4 xv = *(const float4*)(X + (size_t)(row0 + lrow) * K + k0 + lk);
            Xs[lrow][lk + 0] = xv.x; Xs[lrow][lk + 1] = xv.y;
            Xs[lrow][lk + 2] = xv.z; Xs[lrow][lk + 3] = xv.w;
            const float4 wv = *(const float4*)(W + (size_t)(col0 + lrow) * K + k0 + lk);
            Ws[lrow][lk + 0] = wv.x; Ws[lrow][lk + 1] = wv.y;
            Ws[lrow][lk + 2] = wv.z; Ws[lrow][lk + 3] = wv.w;
        }
        __syncthreads();   // tiles visible

        #pragma unroll
        for (int kk = 0; kk < 16; ++kk) {
            float a[4], bb[4];
            #pragma unroll
            for (int i = 0; i < 4; ++i) a[i]  = Xs[ty + 16 * i][kk];
            #pragma unroll
            for (int j = 0; j < 4; ++j) bb[j] = Ws[tx + 16 * j][kk];
            #pragma unroll
            for (int i = 0; i < 4; ++i)
                #pragma unroll
                for (int j = 0; j < 4; ++j)
                    c[i][j] = fmaf(a[i], bb[j], c[i][j]);
        }
    }

    #pragma unroll
    for (int i = 0; i < 4; ++i) {
        const int row = row0 + ty + 16 * i;
        #pragma unroll
        for (int j = 0; j < 4; ++j) {
            const int col = col0 + tx + 16 * j;
            C[(size_t)row * Ncols + col] = c[i][j] + bias[col];
        }
    }
}

// ---------------------------------------------------------------------------
// Flash-style attention with distance-bin bias + key mask.
// Block = 256 threads (4 waves), handles one (b, h, 16-q tile).
// K-tiles of 64 staged in LDS; online softmax per q-row (4 rows per wave,
// lane = k within row for scores/softmax, lane = d for PV).
// ---------------------------------------------------------------------------
__global__ __launch_bounds__(256) void attn_fwd(
    const float* __restrict__ Qp, const float* __restrict__ Kp,
    const float* __restrict__ Vp, const float* __restrict__ dist,
    const int*   __restrict__ mask, const float* __restrict__ demb,
    const float* __restrict__ abias, float* __restrict__ O)
{
    const int qt = blockIdx.x;     // 0..63
    const int h  = blockIdx.y;     // 0..7
    const int b  = blockIdx.z;     // 0..7
    const int q0 = qt * 16;
    const int t    = threadIdx.x;
    const int lane = t & 63;
    const int wave = t >> 6;

    __shared__ float Qs[16][HD_ + 1];
    __shared__ float Ks[64][HD_ + 1];
    __shared__ float Vs[64][HD_ + 1];
    __shared__ float Ss[16][64 + 4];
    __shared__ float demb_s[50 * NH_];

    for (int i = t; i < 50 * NH_; i += 256) demb_s[i] = demb[i];
    for (int i = t; i < 16 * HD_; i += 256) {
        const int r = i >> 6, d = i & 63;
        Qs[r][d] = Qp[((size_t)(b * N_ + q0 + r)) * H_ + h * HD_ + d];
    }
    const float ab = abias[h];

    float m[4], l[4], o[4];
    #pragma unroll
    for (int j = 0; j < 4; ++j) { m[j] = -INFINITY; l[j] = 0.f; o[j] = 0.f; }

    const int ql = t >> 4;   // 0..15 : q row this thread scores
    const int kb = t & 15;   // k base within tile

    for (int k0 = 0; k0 < N_; k0 += 64) {
        __syncthreads();   // previous PV done reading Vs
        for (int i = t; i < 64 * HD_; i += 256) {
            const int r = i >> 6, d = i & 63;
            const size_t base = ((size_t)(b * N_ + k0 + r)) * H_ + h * HD_ + d;
            Ks[r][d] = Kp[base];
            Vs[r][d] = Vp[base];
        }
        __syncthreads();   // K/V tiles visible (Qs from prologue also covered)

        // ---- scores for this tile: thread covers (ql, kb + 16j) ----
        #pragma unroll
        for (int j = 0; j < 4; ++j) {
            const int k = kb + 16 * j;
            float s = 0.f;
            #pragma unroll
            for (int d = 0; d < HD_; ++d) s = fmaf(Qs[ql][d], Ks[k][d], s);
            s *= 0.125f;   // 1/sqrt(64)
            const float dv = dist[((size_t)b * N_ + (q0 + ql)) * N_ + k0 + k];
            int bin = (int)(dv * 10.0f);
            bin = bin < 0 ? 0 : (bin > 49 ? 49 : bin);
            s += demb_s[bin * NH_ + h] + ab;
            if (mask[b * N_ + k0 + k]) s = -1e9f;
            Ss[ql][k] = s;
        }
        __syncthreads();

        // ---- online softmax update: wave owns rows 4*wave..4*wave+3 ----
        #pragma unroll
        for (int j = 0; j < 4; ++j) {
            const int r = wave * 4 + j;
            const float s = Ss[r][lane];
            float tm = s;
            #pragma unroll
            for (int off = 32; off; off >>= 1) tm = fmaxf(tm, __shfl_xor(tm, off, 64));
            const float mnew = fmaxf(m[j], tm);
            const float p = __expf(s - mnew);
            float ts = p;
            #pragma unroll
            for (int off = 32; off; off >>= 1) ts += __shfl_xor(ts, off, 64);
            const float alpha = __expf(m[j] - mnew);   // -inf -> 0 on first tile
            l[j] = l[j] * alpha + ts;
            o[j] *= alpha;
            m[j] = mnew;
            Ss[r][lane] = p;
        }
        __syncthreads();

        // ---- PV: lane = d, accumulate 4 rows sharing each Vs load ----
        {
            const int r0 = wave * 4;
            float a0 = 0.f, a1 = 0.f, a2 = 0.f, a3 = 0.f;
            #pragma unroll 8
            for (int k = 0; k < 64; ++k) {
                const float v = Vs[k][lane];
                a0 = fmaf(Ss[r0 + 0][k], v, a0);
                a1 = fmaf(Ss[r0 + 1][k], v, a1);
                a2 = fmaf(Ss[r0 + 2][k], v, a2);
                a3 = fmaf(Ss[r0 + 3][k], v, a3);
            }
            o[0] += a0; o[1] += a1; o[2] += a2; o[3] += a3;
        }
    }

    #pragma unroll
    for (int j = 0; j < 4; ++j) {
        const int r = wave * 4 + j;
        O[((size_t)(b * N_ + q0 + r)) * H_ + h * HD_ + lane] = o[j] / l[j];
    }
}

// ---------------------------------------------------------------------------
extern "C" void kernel_launch(void* const* d_in, const int* in_sizes, int n_in,
                              void* d_out, int out_size, void* d_ws, size_t ws_size,
                              hipStream_t stream)
{
    const float* x    = (const float*)d_in[0];
    const float* dist = (const float*)d_in[1];
    const int*   mask = (const int*)d_in[2];
    const float* Wq   = (const float*)d_in[3];
    const float* bq   = (const float*)d_in[4];
    const float* Wk   = (const float*)d_in[5];
    const float* bk   = (const float*)d_in[6];
    const float* Wv   = (const float*)d_in[7];
    const float* bv   = (const float*)d_in[8];
    const float* Wo   = (const float*)d_in[9];
    const float* bo   = (const float*)d_in[10];
    const float* demb = (const float*)d_in[11];
    const float* ab   = (const float*)d_in[12];
    float* out = (float*)d_out;

    const size_t mat = (size_t)B_ * N_ * H_;   // 4,194,304 floats
    float* Qb = (float*)d_ws;
    float* Kb = Qb + mat;
    float* Vb = Kb + mat;
    float* Ab = Vb + mat;

    const dim3 blk(256);
    const dim3 ggrid(H_ / 64, (B_ * N_) / 64);   // (8, 128)

    hipLaunchKernelGGL(gemm_xwt, ggrid, blk, 0, stream, x, Wq, bq, Qb, B_ * N_, H_, H_);
    hipLaunchKernelGGL(gemm_xwt, ggrid, blk, 0, stream, x, Wk, bk, Kb, B_ * N_, H_, H_);
    hipLaunchKernelGGL(gemm_xwt, ggrid, blk, 0, stream, x, Wv, bv, Vb, B_ * N_, H_, H_);

    const dim3 agrid(N_ / 16, NH_, B_);          // (64, 8, 8)
    hipLaunchKernelGGL(attn_fwd, agrid, blk, 0, stream,
                       Qb, Kb, Vb, dist, mask, demb, ab, Ab);

    hipLaunchKernelGGL(gemm_xwt, ggrid, blk, 0, stream, Ab, Wo, bo, out, B_ * N_, H_, H_);
}

// Round 2
// 420.514 us; speedup vs baseline: 3.7942x; 3.7942x over previous
//
#include <hip/hip_runtime.h>
#include <hip/hip_bf16.h>
#include <math.h>

#define B_  8
#define N_  1024
#define H_  512
#define NH_ 8
#define HD_ 64

typedef __attribute__((ext_vector_type(8))) short short8;
typedef __attribute__((ext_vector_type(4))) float floatx4;

static __device__ __forceinline__ unsigned short f2bf(float f) {
    __hip_bfloat16 h = __float2bfloat16(f);
    unsigned short u;
    __builtin_memcpy(&u, &h, 2);
    return u;
}

// ---------------------------------------------------------------------------
// dist -> int8 bins, once (shared across heads). bin = clip(int(d*10), 0, 49)
// ---------------------------------------------------------------------------
__global__ __launch_bounds__(256) void bins_kernel(
    const float* __restrict__ dist, unsigned char* __restrict__ bins, int n4)
{
    int i = blockIdx.x * blockDim.x + threadIdx.x;
    const int stride = gridDim.x * blockDim.x;
    for (; i < n4; i += stride) {
        const float4 v = ((const float4*)dist)[i];
        uchar4 r;
        int b0 = (int)(v.x * 10.f); b0 = b0 < 0 ? 0 : (b0 > 49 ? 49 : b0);
        int b1 = (int)(v.y * 10.f); b1 = b1 < 0 ? 0 : (b1 > 49 ? 49 : b1);
        int b2 = (int)(v.z * 10.f); b2 = b2 < 0 ? 0 : (b2 > 49 ? 49 : b2);
        int b3 = (int)(v.w * 10.f); b3 = b3 < 0 ? 0 : (b3 > 49 ? 49 : b3);
        r.x = (unsigned char)b0; r.y = (unsigned char)b1;
        r.z = (unsigned char)b2; r.w = (unsigned char)b3;
        ((uchar4*)bins)[i] = r;
    }
}

// ---------------------------------------------------------------------------
// GEMM: C[M,Ncols] = X[M,K] @ W[Ncols,K]^T + bias  (fp32 out)
// ---------------------------------------------------------------------------
__global__ __launch_bounds__(256) void gemm_xwt(
    const float* __restrict__ X, const float* __restrict__ W,
    const float* __restrict__ bias, float* __restrict__ C,
    int M, int Ncols, int K)
{
    __shared__ float Xs[64][17];
    __shared__ float Ws[64][17];

    const int t   = threadIdx.x;
    const int tx  = t & 15;
    const int ty  = t >> 4;
    const int row0 = blockIdx.y * 64;
    const int col0 = blockIdx.x * 64;
    const int lrow = t >> 2;
    const int lk   = (t & 3) * 4;

    float c[4][4];
    #pragma unroll
    for (int i = 0; i < 4; ++i)
        #pragma unroll
        for (int j = 0; j < 4; ++j) c[i][j] = 0.f;

    for (int k0 = 0; k0 < K; k0 += 16) {
        __syncthreads();
        {
            const float4 xv = *(const float4*)(X + (size_t)(row0 + lrow) * K + k0 + lk);
            Xs[lrow][lk + 0] = xv.x; Xs[lrow][lk + 1] = xv.y;
            Xs[lrow][lk + 2] = xv.z; Xs[lrow][lk + 3] = xv.w;
            const float4 wv = *(const float4*)(W + (size_t)(col0 + lrow) * K + k0 + lk);
            Ws[lrow][lk + 0] = wv.x; Ws[lrow][lk + 1] = wv.y;
            Ws[lrow][lk + 2] = wv.z; Ws[lrow][lk + 3] = wv.w;
        }
        __syncthreads();

        #pragma unroll
        for (int kk = 0; kk < 16; ++kk) {
            float a[4], bb[4];
            #pragma unroll
            for (int i = 0; i < 4; ++i) a[i]  = Xs[ty + 16 * i][kk];
            #pragma unroll
            for (int j = 0; j < 4; ++j) bb[j] = Ws[tx + 16 * j][kk];
            #pragma unroll
            for (int i = 0; i < 4; ++i)
                #pragma unroll
                for (int j = 0; j < 4; ++j)
                    c[i][j] = fmaf(a[i], bb[j], c[i][j]);
        }
    }

    #pragma unroll
    for (int i = 0; i < 4; ++i) {
        const int row = row0 + ty + 16 * i;
        #pragma unroll
        for (int j = 0; j < 4; ++j) {
            const int col = col0 + tx + 16 * j;
            C[(size_t)row * Ncols + col] = c[i][j] + bias[col];
        }
    }
}

// Same GEMM but bf16 output with scale factor (for Q/K/V projections)
__global__ __launch_bounds__(256) void gemm_xwt_bf16(
    const float* __restrict__ X, const float* __restrict__ W,
    const float* __restrict__ bias, __hip_bfloat16* __restrict__ C,
    int M, int Ncols, int K, float scale)
{
    __shared__ float Xs[64][17];
    __shared__ float Ws[64][17];

    const int t   = threadIdx.x;
    const int tx  = t & 15;
    const int ty  = t >> 4;
    const int row0 = blockIdx.y * 64;
    const int col0 = blockIdx.x * 64;
    const int lrow = t >> 2;
    const int lk   = (t & 3) * 4;

    float c[4][4];
    #pragma unroll
    for (int i = 0; i < 4; ++i)
        #pragma unroll
        for (int j = 0; j < 4; ++j) c[i][j] = 0.f;

    for (int k0 = 0; k0 < K; k0 += 16) {
        __syncthreads();
        {
            const float4 xv = *(const float4*)(X + (size_t)(row0 + lrow) * K + k0 + lk);
            Xs[lrow][lk + 0] = xv.x; Xs[lrow][lk + 1] = xv.y;
            Xs[lrow][lk + 2] = xv.z; Xs[lrow][lk + 3] = xv.w;
            const float4 wv = *(const float4*)(W + (size_t)(col0 + lrow) * K + k0 + lk);
            Ws[lrow][lk + 0] = wv.x; Ws[lrow][lk + 1] = wv.y;
            Ws[lrow][lk + 2] = wv.z; Ws[lrow][lk + 3] = wv.w;
        }
        __syncthreads();

        #pragma unroll
        for (int kk = 0; kk < 16; ++kk) {
            float a[4], bb[4];
            #pragma unroll
            for (int i = 0; i < 4; ++i) a[i]  = Xs[ty + 16 * i][kk];
            #pragma unroll
            for (int j = 0; j < 4; ++j) bb[j] = Ws[tx + 16 * j][kk];
            #pragma unroll
            for (int i = 0; i < 4; ++i)
                #pragma unroll
                for (int j = 0; j < 4; ++j)
                    c[i][j] = fmaf(a[i], bb[j], c[i][j]);
        }
    }

    #pragma unroll
    for (int i = 0; i < 4; ++i) {
        const int row = row0 + ty + 16 * i;
        #pragma unroll
        for (int j = 0; j < 4; ++j) {
            const int col = col0 + tx + 16 * j;
            C[(size_t)row * Ncols + col] = __float2bfloat16((c[i][j] + bias[col]) * scale);
        }
    }
}

// ---------------------------------------------------------------------------
// MFMA flash attention. Block = 256 thr (4 waves) = one (b, h, 64-q tile).
// Each wave owns 16 q rows. K-tiles of 64. LDS tiles XOR-swizzled
// (halfword idx ^= (row&7)<<3) for conflict-free ds_read_b128 fragments.
// Fragment layouts (gfx950 16x16x32 bf16):
//   A: row = lane&15,  k = (lane>>4)*8 + j   (8 contiguous bf16 -> b128)
//   B: col = lane&15,  k = (lane>>4)*8 + j
//   D: col = lane&15,  row = (lane>>4)*4 + reg   [m89-verified]
// S-accum and O-accum share the (lane,reg)->q-row mapping, so the online-
// softmax alpha rescale is register-local.
// ---------------------------------------------------------------------------
__global__ __launch_bounds__(256) void attn_mfma(
    const unsigned short* __restrict__ Qg, const unsigned short* __restrict__ Kg,
    const unsigned short* __restrict__ Vg, const unsigned char* __restrict__ bins,
    const int* __restrict__ mask, const float* __restrict__ demb,
    const float* __restrict__ abias, float* __restrict__ O)
{
    const int qt = blockIdx.x;
    const int h  = blockIdx.y;
    const int b  = blockIdx.z;
    const int q0 = qt * 64;
    const int t  = threadIdx.x;
    const int lane = t & 63;
    const int wave = t >> 6;
    const int l15 = lane & 15;
    const int lhi = lane >> 4;   // 0..3

    __shared__ unsigned short Qs[64 * 64];
    __shared__ unsigned short Ks[64 * 64];
    __shared__ unsigned short Vt[64 * 64];   // transposed: [d][k]
    __shared__ unsigned short Ps[4 * 16 * 64];
    __shared__ unsigned char  Bs[64 * 64];   // dist bins, rows = q-local
    __shared__ int            Ms[64];        // key mask for current k-tile
    __shared__ float          db[64];        // demb[bin][h] + attn_bias[h]

    if (t < 50) db[t] = demb[t * NH_ + h] + abias[h];

    // ---- stage Q (already scaled by 1/8 at projection) ----
    {
        const int qr = t >> 2;
        const int d0 = (t & 3) * 16;
        const unsigned short* src = Qg + ((size_t)(b * N_ + q0 + qr)) * H_ + h * HD_ + d0;
        #pragma unroll
        for (int cc = 0; cc < 2; ++cc) {
            const uint4 v = *(const uint4*)(src + 8 * cc);
            const int idx = (qr * 64 + d0 + 8 * cc) ^ ((qr & 7) << 3);
            *(uint4*)&Qs[idx] = v;
        }
    }
    __syncthreads();

    // ---- hoisted Q fragments (constant over k-tiles) ----
    short8 aq[2];
    {
        const int qrow = (wave << 4) + l15;
        #pragma unroll
        for (int ck = 0; ck < 2; ++ck) {
            const int kb = lhi * 8 + 32 * ck;
            const int idx = (qrow * 64 + kb) ^ ((qrow & 7) << 3);
            aq[ck] = *(const short8*)&Qs[idx];
        }
    }

    float m[4], lsum[4];
    floatx4 o4[4];
    #pragma unroll
    for (int r = 0; r < 4; ++r) { m[r] = -INFINITY; lsum[r] = 0.f; }
    #pragma unroll
    for (int nd = 0; nd < 4; ++nd) o4[nd] = (floatx4)0.f;

    for (int k0 = 0; k0 < N_; k0 += 64) {
        __syncthreads();   // previous iteration's reads of Ks/Vt/Bs/Ms done
        {
            const int kr = t >> 2;
            const int d0 = (t & 3) * 16;
            const unsigned short* ksrc = Kg + ((size_t)(b * N_ + k0 + kr)) * H_ + h * HD_ + d0;
            const unsigned short* vsrc = Vg + ((size_t)(b * N_ + k0 + kr)) * H_ + h * HD_ + d0;
            #pragma unroll
            for (int cc = 0; cc < 2; ++cc) {
                const uint4 kv = *(const uint4*)(ksrc + 8 * cc);
                const int idx = (kr * 64 + d0 + 8 * cc) ^ ((kr & 7) << 3);
                *(uint4*)&Ks[idx] = kv;
                const short8 vv = *(const short8*)(vsrc + 8 * cc);
                #pragma unroll
                for (int j = 0; j < 8; ++j) {
                    const int d = d0 + 8 * cc + j;
                    Vt[d * 64 + (kr ^ ((d & 7) << 3))] = (unsigned short)vv[j];
                }
            }
            // bins tile (rows = q-local), 16B per thread
            *(uint4*)&Bs[kr * 64 + d0] =
                *(const uint4*)(bins + ((size_t)(b * N_ + q0 + kr)) * N_ + k0 + d0);
            if (t < 64) Ms[t] = mask[b * N_ + k0 + t];
        }
        __syncthreads();

        // ---- S = (Q/8) K^T via MFMA : s4[kn][r] = S[q(lhi,r)][kn*16+l15] ----
        floatx4 s4[4];
        #pragma unroll
        for (int kn = 0; kn < 4; ++kn) {
            const int kcol = kn * 16 + l15;
            floatx4 acc = (floatx4)0.f;
            #pragma unroll
            for (int ck = 0; ck < 2; ++ck) {
                const int kb = lhi * 8 + 32 * ck;
                const int idx = (kcol * 64 + kb) ^ ((kcol & 7) << 3);
                const short8 bk = *(const short8*)&Ks[idx];
                acc = __builtin_amdgcn_mfma_f32_16x16x32_bf16(aq[ck], bk, acc, 0, 0, 0);
            }
            s4[kn] = acc;
        }

        // ---- + distance bias, key mask ----
        #pragma unroll
        for (int kn = 0; kn < 4; ++kn) {
            const int k = kn * 16 + l15;
            const int msk = Ms[k];
            #pragma unroll
            for (int r = 0; r < 4; ++r) {
                const int qlb = (wave << 4) + lhi * 4 + r;
                const int bin = Bs[qlb * 64 + k];
                const float s = s4[kn][r] + db[bin];
                s4[kn][r] = msk ? -1e9f : s;
            }
        }

        // ---- online softmax (row spread over 16 lanes x 4 regs) ----
        #pragma unroll
        for (int r = 0; r < 4; ++r) {
            float tm = fmaxf(fmaxf(s4[0][r], s4[1][r]), fmaxf(s4[2][r], s4[3][r]));
            tm = fmaxf(tm, __shfl_xor(tm, 1, 64));
            tm = fmaxf(tm, __shfl_xor(tm, 2, 64));
            tm = fmaxf(tm, __shfl_xor(tm, 4, 64));
            tm = fmaxf(tm, __shfl_xor(tm, 8, 64));
            const float mnew = fmaxf(m[r], tm);
            float ts = 0.f;
            #pragma unroll
            for (int kn = 0; kn < 4; ++kn) {
                const float p = __expf(s4[kn][r] - mnew);
                s4[kn][r] = p;
                ts += p;
            }
            ts += __shfl_xor(ts, 1, 64);
            ts += __shfl_xor(ts, 2, 64);
            ts += __shfl_xor(ts, 4, 64);
            ts += __shfl_xor(ts, 8, 64);
            const float alpha = __expf(m[r] - mnew);
            lsum[r] = lsum[r] * alpha + ts;
            m[r] = mnew;
            #pragma unroll
            for (int nd = 0; nd < 4; ++nd) o4[nd][r] *= alpha;
        }

        // ---- P -> LDS (bf16, per-wave region, no barrier needed) ----
        #pragma unroll
        for (int kn = 0; kn < 4; ++kn) {
            const int k = kn * 16 + l15;
            #pragma unroll
            for (int r = 0; r < 4; ++r) {
                const int ql = lhi * 4 + r;
                Ps[(wave << 10) + ql * 64 + (k ^ ((ql & 7) << 3))] = f2bf(s4[kn][r]);
            }
        }

        // ---- O += P V via MFMA ----
        #pragma unroll
        for (int ck = 0; ck < 2; ++ck) {
            const int kb = lhi * 8 + 32 * ck;
            const int aidx = (wave << 10) + (l15 * 64 + (kb ^ ((l15 & 7) << 3)));
            const short8 ap = *(const short8*)&Ps[aidx];
            #pragma unroll
            for (int nd = 0; nd < 4; ++nd) {
                const int dcol = nd * 16 + l15;
                const int vidx = (dcol * 64 + kb) ^ ((dcol & 7) << 3);
                const short8 bv = *(const short8*)&Vt[vidx];
                o4[nd] = __builtin_amdgcn_mfma_f32_16x16x32_bf16(ap, bv, o4[nd], 0, 0, 0);
            }
        }
    }

    float inv[4];
    #pragma unroll
    for (int r = 0; r < 4; ++r) inv[r] = 1.f / lsum[r];
    #pragma unroll
    for (int nd = 0; nd < 4; ++nd) {
        const int d = nd * 16 + l15;
        #pragma unroll
        for (int r = 0; r < 4; ++r) {
            const int q = q0 + (wave << 4) + lhi * 4 + r;
            O[((size_t)(b * N_ + q)) * H_ + h * HD_ + d] = o4[nd][r] * inv[r];
        }
    }
}

// ---------------------------------------------------------------------------
extern "C" void kernel_launch(void* const* d_in, const int* in_sizes, int n_in,
                              void* d_out, int out_size, void* d_ws, size_t ws_size,
                              hipStream_t stream)
{
    const float* x    = (const float*)d_in[0];
    const float* dist = (const float*)d_in[1];
    const int*   mask = (const int*)d_in[2];
    const float* Wq   = (const float*)d_in[3];
    const float* bq   = (const float*)d_in[4];
    const float* Wk   = (const float*)d_in[5];
    const float* bk   = (const float*)d_in[6];
    const float* Wv   = (const float*)d_in[7];
    const float* bv   = (const float*)d_in[8];
    const float* Wo   = (const float*)d_in[9];
    const float* bo   = (const float*)d_in[10];
    const float* demb = (const float*)d_in[11];
    const float* ab   = (const float*)d_in[12];
    float* out = (float*)d_out;

    const size_t mat = (size_t)B_ * N_ * H_;   // 4,194,304 elements
    __hip_bfloat16* Qb = (__hip_bfloat16*)d_ws;
    __hip_bfloat16* Kb = Qb + mat;
    __hip_bfloat16* Vb = Kb + mat;
    float* Ab = (float*)(Vb + mat);
    unsigned char* binsb = (unsigned char*)(Ab + mat);

    const dim3 blk(256);
    const dim3 ggrid(H_ / 64, (B_ * N_) / 64);   // (8, 128)

    hipLaunchKernelGGL(bins_kernel, dim3(2048), blk, 0, stream,
                       dist, binsb, (B_ * N_ * N_) / 4);
    hipLaunchKernelGGL(gemm_xwt_bf16, ggrid, blk, 0, stream, x, Wq, bq, Qb,
                       B_ * N_, H_, H_, 0.125f);
    hipLaunchKernelGGL(gemm_xwt_bf16, ggrid, blk, 0, stream, x, Wk, bk, Kb,
                       B_ * N_, H_, H_, 1.0f);
    hipLaunchKernelGGL(gemm_xwt_bf16, ggrid, blk, 0, stream, x, Wv, bv, Vb,
                       B_ * N_, H_, H_, 1.0f);

    const dim3 agrid(N_ / 64, NH_, B_);          // (16, 8, 8)
    hipLaunchKernelGGL(attn_mfma, agrid, blk, 0, stream,
                       (const unsigned short*)Qb, (const unsigned short*)Kb,
                       (const unsigned short*)Vb, binsb, mask, demb, ab, Ab);

    hipLaunchKernelGGL(gemm_xwt, ggrid, blk, 0, stream, Ab, Wo, bo, out,
                       B_ * N_, H_, H_);
}

// Round 3
// 144.614 us; speedup vs baseline: 11.0330x; 2.9078x over previous
//
#include <hip/hip_runtime.h>
#include <hip/hip_bf16.h>
#include <math.h>

#define B_  8
#define N_  1024
#define H_  512
#define NH_ 8
#define HD_ 64

typedef __attribute__((ext_vector_type(8))) short short8;
typedef __attribute__((ext_vector_type(4))) float floatx4;

#define GPTR(p) ((const __attribute__((address_space(1))) void*)(p))
#define LPTR(p) ((__attribute__((address_space(3))) void*)(p))

static __device__ __forceinline__ unsigned short f2bf(float f) {
    __hip_bfloat16 h = __float2bfloat16(f);
    unsigned short u;
    __builtin_memcpy(&u, &h, 2);
    return u;
}

// ---------------------------------------------------------------------------
// fp32 -> bf16 for x (4194304 elems) and the 4 weight matrices (262144 each),
// into one contiguous bf16 blob: [xb | Wq | Wk | Wv | Wo].
// ---------------------------------------------------------------------------
__global__ __launch_bounds__(256) void cvt_all(
    const float* __restrict__ x,  const float* __restrict__ wq,
    const float* __restrict__ wk, const float* __restrict__ wv,
    const float* __restrict__ wo, unsigned short* __restrict__ dst)
{
    const int n4 = (4194304 + 4 * 262144) / 4;   // 1310720
    int i = blockIdx.x * blockDim.x + threadIdx.x;
    const int stride = gridDim.x * blockDim.x;
    for (; i < n4; i += stride) {
        const int e = i * 4;
        const float* src;
        if (e < 4194304) {
            src = x + e;
        } else {
            const int rel = e - 4194304;
            const int w = rel >> 18;
            const int off = rel & 262143;
            src = (w == 0 ? wq : w == 1 ? wk : w == 2 ? wv : wo) + off;
        }
        const float4 v = *(const float4*)src;
        ushort4 r;
        r.x = f2bf(v.x); r.y = f2bf(v.y); r.z = f2bf(v.z); r.w = f2bf(v.w);
        *(ushort4*)(dst + e) = r;
    }
}

// ---------------------------------------------------------------------------
// dist -> int8 bins: clip(int(d*10), 0, 49)
// ---------------------------------------------------------------------------
__global__ __launch_bounds__(256) void bins_kernel(
    const float* __restrict__ dist, unsigned char* __restrict__ bins, int n4)
{
    int i = blockIdx.x * blockDim.x + threadIdx.x;
    const int stride = gridDim.x * blockDim.x;
    for (; i < n4; i += stride) {
        const float4 v = ((const float4*)dist)[i];
        uchar4 r;
        int b0 = (int)(v.x * 10.f); b0 = b0 < 0 ? 0 : (b0 > 49 ? 49 : b0);
        int b1 = (int)(v.y * 10.f); b1 = b1 < 0 ? 0 : (b1 > 49 ? 49 : b1);
        int b2 = (int)(v.z * 10.f); b2 = b2 < 0 ? 0 : (b2 > 49 ? 49 : b2);
        int b3 = (int)(v.w * 10.f); b3 = b3 < 0 ? 0 : (b3 > 49 ? 49 : b3);
        r.x = (unsigned char)b0; r.y = (unsigned char)b1;
        r.z = (unsigned char)b2; r.w = (unsigned char)b3;
        ((uchar4*)bins)[i] = r;
    }
}

// ---------------------------------------------------------------------------
// MFMA GEMM core (m97 structure): C[M,N] = A[M,K] @ W[N,K]^T + bias
// 128x128 tile, BK=32, 256 threads (4 waves, 2x2), global_load_lds width 16.
// Fragment layouts (verified in attn): A/B: idx=lane&15, k=(lane>>4)*8+j;
// D: col=lane&15, row=(lane>>4)*4+reg.
// ---------------------------------------------------------------------------
template <int BF16OUT>
static __device__ __forceinline__ void gemm_core(
    const unsigned short* __restrict__ A, const unsigned short* __restrict__ W,
    const float* __restrict__ bias, void* __restrict__ C,
    int Ncols, int K, float scale, int row0, int col0)
{
    __shared__ unsigned short As[128 * 32];
    __shared__ unsigned short Bs[128 * 32];

    const int t    = threadIdx.x;
    const int lane = t & 63;
    const int wave = t >> 6;
    const int wr   = wave >> 1;
    const int wc   = wave & 1;
    const int l15  = lane & 15;
    const int lhi  = lane >> 4;

    // staging: wave w covers rows w*32 .. w*32+31 (2 iters of 16 rows)
    const int srow = wave * 32 + (lane >> 2);
    const int sk   = (lane & 3) * 8;
    const unsigned short* gA = A + (size_t)(row0 + srow) * K + sk;
    const unsigned short* gB = W + (size_t)(col0 + srow) * K + sk;

    floatx4 acc[4][4];
    #pragma unroll
    for (int m = 0; m < 4; ++m)
        #pragma unroll
        for (int n = 0; n < 4; ++n) acc[m][n] = (floatx4)0.f;

    for (int k0 = 0; k0 < K; k0 += 32) {
        __syncthreads();
        #pragma unroll
        for (int i = 0; i < 2; ++i) {
            __builtin_amdgcn_global_load_lds(GPTR(gA + (size_t)(i * 16) * K + k0),
                                             LPTR(&As[(wave * 32 + i * 16) * 32]), 16, 0, 0);
            __builtin_amdgcn_global_load_lds(GPTR(gB + (size_t)(i * 16) * K + k0),
                                             LPTR(&Bs[(wave * 32 + i * 16) * 32]), 16, 0, 0);
        }
        __syncthreads();

        short8 af[4], bf[4];
        #pragma unroll
        for (int m = 0; m < 4; ++m)
            af[m] = *(const short8*)&As[(wr * 64 + m * 16 + l15) * 32 + lhi * 8];
        #pragma unroll
        for (int n = 0; n < 4; ++n)
            bf[n] = *(const short8*)&Bs[(wc * 64 + n * 16 + l15) * 32 + lhi * 8];
        #pragma unroll
        for (int m = 0; m < 4; ++m)
            #pragma unroll
            for (int n = 0; n < 4; ++n)
                acc[m][n] = __builtin_amdgcn_mfma_f32_16x16x32_bf16(af[m], bf[n], acc[m][n], 0, 0, 0);
    }

    #pragma unroll
    for (int n = 0; n < 4; ++n) {
        const int col = col0 + wc * 64 + n * 16 + l15;
        const float bv = bias[col];
        #pragma unroll
        for (int m = 0; m < 4; ++m) {
            #pragma unroll
            for (int r = 0; r < 4; ++r) {
                const int row = row0 + wr * 64 + m * 16 + lhi * 4 + r;
                const float v = (acc[m][n][r] + bv) * scale;
                if (BF16OUT)
                    ((unsigned short*)C)[(size_t)row * Ncols + col] = f2bf(v);
                else
                    ((float*)C)[(size_t)row * Ncols + col] = v;
            }
        }
    }
}

// fused Q/K/V projection: blockIdx.z selects weight/bias/output/scale
__global__ __launch_bounds__(256) void gemm_qkv(
    const unsigned short* __restrict__ xb,
    const unsigned short* __restrict__ Wq, const unsigned short* __restrict__ Wk,
    const unsigned short* __restrict__ Wv,
    const float* __restrict__ bq, const float* __restrict__ bk,
    const float* __restrict__ bv,
    unsigned short* __restrict__ Qb, unsigned short* __restrict__ Kb,
    unsigned short* __restrict__ Vb)
{
    const int z = blockIdx.z;
    const unsigned short* W = z == 0 ? Wq : (z == 1 ? Wk : Wv);
    const float* bias       = z == 0 ? bq : (z == 1 ? bk : bv);
    unsigned short* C       = z == 0 ? Qb : (z == 1 ? Kb : Vb);
    const float scale       = z == 0 ? 0.125f : 1.0f;   // fold 1/sqrt(64) into Q
    gemm_core<1>(xb, W, bias, C, H_, H_, scale, blockIdx.y * 128, blockIdx.x * 128);
}

// final output projection: bf16 in, fp32 out
__global__ __launch_bounds__(256) void gemm_out(
    const unsigned short* __restrict__ Ab, const unsigned short* __restrict__ Wo,
    const float* __restrict__ bo, float* __restrict__ out)
{
    gemm_core<0>(Ab, Wo, bo, out, H_, H_, 1.0f, blockIdx.y * 128, blockIdx.x * 128);
}

// ---------------------------------------------------------------------------
// MFMA flash attention (unchanged from R2 except bf16 output).
// ---------------------------------------------------------------------------
__global__ __launch_bounds__(256) void attn_mfma(
    const unsigned short* __restrict__ Qg, const unsigned short* __restrict__ Kg,
    const unsigned short* __restrict__ Vg, const unsigned char* __restrict__ bins,
    const int* __restrict__ mask, const float* __restrict__ demb,
    const float* __restrict__ abias, unsigned short* __restrict__ O)
{
    const int qt = blockIdx.x;
    const int h  = blockIdx.y;
    const int b  = blockIdx.z;
    const int q0 = qt * 64;
    const int t  = threadIdx.x;
    const int lane = t & 63;
    const int wave = t >> 6;
    const int l15 = lane & 15;
    const int lhi = lane >> 4;

    __shared__ unsigned short Qs[64 * 64];
    __shared__ unsigned short Ks[64 * 64];
    __shared__ unsigned short Vt[64 * 64];   // transposed: [d][k]
    __shared__ unsigned short Ps[4 * 16 * 64];
    __shared__ unsigned char  Bs[64 * 64];   // dist bins, rows = q-local
    __shared__ int            Ms[64];
    __shared__ float          db[64];

    if (t < 50) db[t] = demb[t * NH_ + h] + abias[h];

    {
        const int qr = t >> 2;
        const int d0 = (t & 3) * 16;
        const unsigned short* src = Qg + ((size_t)(b * N_ + q0 + qr)) * H_ + h * HD_ + d0;
        #pragma unroll
        for (int cc = 0; cc < 2; ++cc) {
            const uint4 v = *(const uint4*)(src + 8 * cc);
            const int idx = (qr * 64 + d0 + 8 * cc) ^ ((qr & 7) << 3);
            *(uint4*)&Qs[idx] = v;
        }
    }
    __syncthreads();

    short8 aq[2];
    {
        const int qrow = (wave << 4) + l15;
        #pragma unroll
        for (int ck = 0; ck < 2; ++ck) {
            const int kb = lhi * 8 + 32 * ck;
            const int idx = (qrow * 64 + kb) ^ ((qrow & 7) << 3);
            aq[ck] = *(const short8*)&Qs[idx];
        }
    }

    float m[4], lsum[4];
    floatx4 o4[4];
    #pragma unroll
    for (int r = 0; r < 4; ++r) { m[r] = -INFINITY; lsum[r] = 0.f; }
    #pragma unroll
    for (int nd = 0; nd < 4; ++nd) o4[nd] = (floatx4)0.f;

    for (int k0 = 0; k0 < N_; k0 += 64) {
        __syncthreads();
        {
            const int kr = t >> 2;
            const int d0 = (t & 3) * 16;
            const unsigned short* ksrc = Kg + ((size_t)(b * N_ + k0 + kr)) * H_ + h * HD_ + d0;
            const unsigned short* vsrc = Vg + ((size_t)(b * N_ + k0 + kr)) * H_ + h * HD_ + d0;
            #pragma unroll
            for (int cc = 0; cc < 2; ++cc) {
                const uint4 kv = *(const uint4*)(ksrc + 8 * cc);
                const int idx = (kr * 64 + d0 + 8 * cc) ^ ((kr & 7) << 3);
                *(uint4*)&Ks[idx] = kv;
                const short8 vv = *(const short8*)(vsrc + 8 * cc);
                #pragma unroll
                for (int j = 0; j < 8; ++j) {
                    const int d = d0 + 8 * cc + j;
                    Vt[d * 64 + (kr ^ ((d & 7) << 3))] = (unsigned short)vv[j];
                }
            }
            *(uint4*)&Bs[kr * 64 + d0] =
                *(const uint4*)(bins + ((size_t)(b * N_ + q0 + kr)) * N_ + k0 + d0);
            if (t < 64) Ms[t] = mask[b * N_ + k0 + t];
        }
        __syncthreads();

        floatx4 s4[4];
        #pragma unroll
        for (int kn = 0; kn < 4; ++kn) {
            const int kcol = kn * 16 + l15;
            floatx4 acc = (floatx4)0.f;
            #pragma unroll
            for (int ck = 0; ck < 2; ++ck) {
                const int kb = lhi * 8 + 32 * ck;
                const int idx = (kcol * 64 + kb) ^ ((kcol & 7) << 3);
                const short8 bk = *(const short8*)&Ks[idx];
                acc = __builtin_amdgcn_mfma_f32_16x16x32_bf16(aq[ck], bk, acc, 0, 0, 0);
            }
            s4[kn] = acc;
        }

        #pragma unroll
        for (int kn = 0; kn < 4; ++kn) {
            const int k = kn * 16 + l15;
            const int msk = Ms[k];
            #pragma unroll
            for (int r = 0; r < 4; ++r) {
                const int qlb = (wave << 4) + lhi * 4 + r;
                const int bin = Bs[qlb * 64 + k];
                const float s = s4[kn][r] + db[bin];
                s4[kn][r] = msk ? -1e9f : s;
            }
        }

        #pragma unroll
        for (int r = 0; r < 4; ++r) {
            float tm = fmaxf(fmaxf(s4[0][r], s4[1][r]), fmaxf(s4[2][r], s4[3][r]));
            tm = fmaxf(tm, __shfl_xor(tm, 1, 64));
            tm = fmaxf(tm, __shfl_xor(tm, 2, 64));
            tm = fmaxf(tm, __shfl_xor(tm, 4, 64));
            tm = fmaxf(tm, __shfl_xor(tm, 8, 64));
            const float mnew = fmaxf(m[r], tm);
            float ts = 0.f;
            #pragma unroll
            for (int kn = 0; kn < 4; ++kn) {
                const float p = __expf(s4[kn][r] - mnew);
                s4[kn][r] = p;
                ts += p;
            }
            ts += __shfl_xor(ts, 1, 64);
            ts += __shfl_xor(ts, 2, 64);
            ts += __shfl_xor(ts, 4, 64);
            ts += __shfl_xor(ts, 8, 64);
            const float alpha = __expf(m[r] - mnew);
            lsum[r] = lsum[r] * alpha + ts;
            m[r] = mnew;
            #pragma unroll
            for (int nd = 0; nd < 4; ++nd) o4[nd][r] *= alpha;
        }

        #pragma unroll
        for (int kn = 0; kn < 4; ++kn) {
            const int k = kn * 16 + l15;
            #pragma unroll
            for (int r = 0; r < 4; ++r) {
                const int ql = lhi * 4 + r;
                Ps[(wave << 10) + ql * 64 + (k ^ ((ql & 7) << 3))] = f2bf(s4[kn][r]);
            }
        }

        #pragma unroll
        for (int ck = 0; ck < 2; ++ck) {
            const int kb = lhi * 8 + 32 * ck;
            const int aidx = (wave << 10) + (l15 * 64 + (kb ^ ((l15 & 7) << 3)));
            const short8 ap = *(const short8*)&Ps[aidx];
            #pragma unroll
            for (int nd = 0; nd < 4; ++nd) {
                const int dcol = nd * 16 + l15;
                const int vidx = (dcol * 64 + kb) ^ ((dcol & 7) << 3);
                const short8 bv = *(const short8*)&Vt[vidx];
                o4[nd] = __builtin_amdgcn_mfma_f32_16x16x32_bf16(ap, bv, o4[nd], 0, 0, 0);
            }
        }
    }

    float inv[4];
    #pragma unroll
    for (int r = 0; r < 4; ++r) inv[r] = 1.f / lsum[r];
    #pragma unroll
    for (int nd = 0; nd < 4; ++nd) {
        const int d = nd * 16 + l15;
        #pragma unroll
        for (int r = 0; r < 4; ++r) {
            const int q = q0 + (wave << 4) + lhi * 4 + r;
            O[((size_t)(b * N_ + q)) * H_ + h * HD_ + d] = f2bf(o4[nd][r] * inv[r]);
        }
    }
}

// ---------------------------------------------------------------------------
extern "C" void kernel_launch(void* const* d_in, const int* in_sizes, int n_in,
                              void* d_out, int out_size, void* d_ws, size_t ws_size,
                              hipStream_t stream)
{
    const float* x    = (const float*)d_in[0];
    const float* dist = (const float*)d_in[1];
    const int*   mask = (const int*)d_in[2];
    const float* Wq   = (const float*)d_in[3];
    const float* bq   = (const float*)d_in[4];
    const float* Wk   = (const float*)d_in[5];
    const float* bk   = (const float*)d_in[6];
    const float* Wv   = (const float*)d_in[7];
    const float* bv   = (const float*)d_in[8];
    const float* Wo   = (const float*)d_in[9];
    const float* bo   = (const float*)d_in[10];
    const float* demb = (const float*)d_in[11];
    const float* ab   = (const float*)d_in[12];
    float* out = (float*)d_out;

    const size_t mat = (size_t)B_ * N_ * H_;         // 4,194,304
    const size_t wsz = (size_t)H_ * H_;              //   262,144

    unsigned short* blob = (unsigned short*)d_ws;    // [xb | Wq | Wk | Wv | Wo]
    unsigned short* xb  = blob;
    unsigned short* Wqb = blob + mat;
    unsigned short* Wkb = Wqb + wsz;
    unsigned short* Wvb = Wkb + wsz;
    unsigned short* Wob = Wvb + wsz;
    unsigned short* Qb  = Wob + wsz;
    unsigned short* Kb  = Qb + mat;
    unsigned short* Vb  = Kb + mat;
    unsigned short* Ab  = Vb + mat;
    unsigned char*  binsb = (unsigned char*)(Ab + mat);

    const dim3 blk(256);

    hipLaunchKernelGGL(cvt_all, dim3(1024), blk, 0, stream, x, Wq, Wk, Wv, Wo, blob);
    hipLaunchKernelGGL(bins_kernel, dim3(2048), blk, 0, stream,
                       dist, binsb, (B_ * N_ * N_) / 4);

    const dim3 qgrid(H_ / 128, (B_ * N_) / 128, 3);  // (4, 64, 3)
    hipLaunchKernelGGL(gemm_qkv, qgrid, blk, 0, stream,
                       xb, Wqb, Wkb, Wvb, bq, bk, bv, Qb, Kb, Vb);

    const dim3 agrid(N_ / 64, NH_, B_);              // (16, 8, 8)
    hipLaunchKernelGGL(attn_mfma, agrid, blk, 0, stream,
                       Qb, Kb, Vb, binsb, mask, demb, ab, Ab);

    const dim3 ogrid(H_ / 128, (B_ * N_) / 128, 1);  // (4, 64)
    hipLaunchKernelGGL(gemm_out, ogrid, blk, 0, stream, Ab, Wob, bo, out);
}

// Round 4
// 129.765 us; speedup vs baseline: 12.2955x; 1.1144x over previous
//
#include <hip/hip_runtime.h>
#include <hip/hip_bf16.h>
#include <math.h>

#define B_  8
#define N_  1024
#define H_  512
#define NH_ 8
#define HD_ 64

typedef __attribute__((ext_vector_type(8))) short short8;
typedef __attribute__((ext_vector_type(4))) short short4_t;
typedef __attribute__((ext_vector_type(4))) float floatx4;

#define GPTR(p) ((const __attribute__((address_space(1))) void*)(p))
#define LPTR(p) ((__attribute__((address_space(3))) void*)(p))

// ds_read_b64_tr_b16: lane l elem j <- lds[region + j*16 + (l&15)] (bf16 elems),
// region = per-lane addr pattern base + (l>>4)*256B + (l&15)*8B + IMM.
#define TRB16(dst, addr, IMM) \
    asm volatile("ds_read_b64_tr_b16 %0, %1 offset:" IMM \
                 : "=v"(dst) : "v"(addr) : "memory")

static __device__ __forceinline__ unsigned short f2bf(float f) {
    __hip_bfloat16 h = __float2bfloat16(f);
    unsigned short u;
    __builtin_memcpy(&u, &h, 2);
    return u;
}

// ---------------------------------------------------------------------------
// fp32 -> bf16 for x and the 4 weights into one blob [xb | Wq | Wk | Wv | Wo]
// ---------------------------------------------------------------------------
__global__ __launch_bounds__(256) void cvt_all(
    const float* __restrict__ x,  const float* __restrict__ wq,
    const float* __restrict__ wk, const float* __restrict__ wv,
    const float* __restrict__ wo, unsigned short* __restrict__ dst)
{
    const int n4 = (4194304 + 4 * 262144) / 4;
    int i = blockIdx.x * blockDim.x + threadIdx.x;
    const int stride = gridDim.x * blockDim.x;
    for (; i < n4; i += stride) {
        const int e = i * 4;
        const float* src;
        if (e < 4194304) {
            src = x + e;
        } else {
            const int rel = e - 4194304;
            const int w = rel >> 18;
            const int off = rel & 262143;
            src = (w == 0 ? wq : w == 1 ? wk : w == 2 ? wv : wo) + off;
        }
        const float4 v = *(const float4*)src;
        ushort4 r;
        r.x = f2bf(v.x); r.y = f2bf(v.y); r.z = f2bf(v.z); r.w = f2bf(v.w);
        *(ushort4*)(dst + e) = r;
    }
}

// ---------------------------------------------------------------------------
// binsT[b][k][q] = mask[b][k] ? 255 : clip(int(dist[b][q][k]*10),0,49)
// 64x64 tiled transpose through LDS; mask folded per key row.
// ---------------------------------------------------------------------------
__global__ __launch_bounds__(256) void binsT_kernel(
    const float* __restrict__ dist, const int* __restrict__ mask,
    unsigned char* __restrict__ binsT)
{
    const int kt = blockIdx.x, qt = blockIdx.y, b = blockIdx.z;
    const int q0 = qt * 64, k0 = kt * 64;
    __shared__ unsigned char Lb[64][80];

    const int t = threadIdx.x;
    {
        const int qr = t >> 2, kc = (t & 3) * 16;
        const float* src = dist + ((size_t)(b * N_) + q0 + qr) * N_ + k0 + kc;
        unsigned w[4];
        #pragma unroll
        for (int i = 0; i < 4; ++i) {
            const float4 v = *(const float4*)(src + 4 * i);
            int b0 = (int)(v.x * 10.f); b0 = b0 < 0 ? 0 : (b0 > 49 ? 49 : b0);
            int b1 = (int)(v.y * 10.f); b1 = b1 < 0 ? 0 : (b1 > 49 ? 49 : b1);
            int b2 = (int)(v.z * 10.f); b2 = b2 < 0 ? 0 : (b2 > 49 ? 49 : b2);
            int b3 = (int)(v.w * 10.f); b3 = b3 < 0 ? 0 : (b3 > 49 ? 49 : b3);
            w[i] = (unsigned)b0 | ((unsigned)b1 << 8) | ((unsigned)b2 << 16) | ((unsigned)b3 << 24);
        }
        uint4 u; u.x = w[0]; u.y = w[1]; u.z = w[2]; u.w = w[3];
        *(uint4*)&Lb[qr][kc] = u;
    }
    __syncthreads();
    {
        const int kr = t >> 2, qc = (t & 3) * 16;
        uint4 u;
        if (mask[b * N_ + k0 + kr]) {
            u.x = u.y = u.z = u.w = 0xFFFFFFFFu;
        } else {
            unsigned w[4];
            #pragma unroll
            for (int i = 0; i < 4; ++i) {
                w[i] = (unsigned)Lb[qc + 4 * i + 0][kr]
                     | ((unsigned)Lb[qc + 4 * i + 1][kr] << 8)
                     | ((unsigned)Lb[qc + 4 * i + 2][kr] << 16)
                     | ((unsigned)Lb[qc + 4 * i + 3][kr] << 24);
            }
            u.x = w[0]; u.y = w[1]; u.z = w[2]; u.w = w[3];
        }
        *(uint4*)(binsT + ((size_t)(b * N_) + k0 + kr) * N_ + q0 + qc) = u;
    }
}

// ---------------------------------------------------------------------------
// MFMA GEMM (m97 structure), unchanged from R3.
// ---------------------------------------------------------------------------
template <int BF16OUT>
static __device__ __forceinline__ void gemm_core(
    const unsigned short* __restrict__ A, const unsigned short* __restrict__ W,
    const float* __restrict__ bias, void* __restrict__ C,
    int Ncols, int K, float scale, int row0, int col0)
{
    __shared__ unsigned short As[128 * 32];
    __shared__ unsigned short Bs[128 * 32];

    const int t    = threadIdx.x;
    const int lane = t & 63;
    const int wave = t >> 6;
    const int wr   = wave >> 1;
    const int wc   = wave & 1;
    const int l15  = lane & 15;
    const int lhi  = lane >> 4;

    const int srow = wave * 32 + (lane >> 2);
    const int sk   = (lane & 3) * 8;
    const unsigned short* gA = A + (size_t)(row0 + srow) * K + sk;
    const unsigned short* gB = W + (size_t)(col0 + srow) * K + sk;

    floatx4 acc[4][4];
    #pragma unroll
    for (int m = 0; m < 4; ++m)
        #pragma unroll
        for (int n = 0; n < 4; ++n) acc[m][n] = (floatx4)0.f;

    for (int k0 = 0; k0 < K; k0 += 32) {
        __syncthreads();
        #pragma unroll
        for (int i = 0; i < 2; ++i) {
            __builtin_amdgcn_global_load_lds(GPTR(gA + (size_t)(i * 16) * K + k0),
                                             LPTR(&As[(wave * 32 + i * 16) * 32]), 16, 0, 0);
            __builtin_amdgcn_global_load_lds(GPTR(gB + (size_t)(i * 16) * K + k0),
                                             LPTR(&Bs[(wave * 32 + i * 16) * 32]), 16, 0, 0);
        }
        __syncthreads();

        short8 af[4], bf[4];
        #pragma unroll
        for (int m = 0; m < 4; ++m)
            af[m] = *(const short8*)&As[(wr * 64 + m * 16 + l15) * 32 + lhi * 8];
        #pragma unroll
        for (int n = 0; n < 4; ++n)
            bf[n] = *(const short8*)&Bs[(wc * 64 + n * 16 + l15) * 32 + lhi * 8];
        #pragma unroll
        for (int m = 0; m < 4; ++m)
            #pragma unroll
            for (int n = 0; n < 4; ++n)
                acc[m][n] = __builtin_amdgcn_mfma_f32_16x16x32_bf16(af[m], bf[n], acc[m][n], 0, 0, 0);
    }

    #pragma unroll
    for (int n = 0; n < 4; ++n) {
        const int col = col0 + wc * 64 + n * 16 + l15;
        const float bvv = bias[col];
        #pragma unroll
        for (int m = 0; m < 4; ++m) {
            #pragma unroll
            for (int r = 0; r < 4; ++r) {
                const int row = row0 + wr * 64 + m * 16 + lhi * 4 + r;
                const float v = (acc[m][n][r] + bvv) * scale;
                if (BF16OUT)
                    ((unsigned short*)C)[(size_t)row * Ncols + col] = f2bf(v);
                else
                    ((float*)C)[(size_t)row * Ncols + col] = v;
            }
        }
    }
}

__global__ __launch_bounds__(256) void gemm_qkv(
    const unsigned short* __restrict__ xb,
    const unsigned short* __restrict__ Wq, const unsigned short* __restrict__ Wk,
    const unsigned short* __restrict__ Wv,
    const float* __restrict__ bq, const float* __restrict__ bk,
    const float* __restrict__ bv,
    unsigned short* __restrict__ Qb, unsigned short* __restrict__ Kb,
    unsigned short* __restrict__ Vb)
{
    const int z = blockIdx.z;
    const unsigned short* W = z == 0 ? Wq : (z == 1 ? Wk : Wv);
    const float* bias       = z == 0 ? bq : (z == 1 ? bk : bv);
    unsigned short* C       = z == 0 ? Qb : (z == 1 ? Kb : Vb);
    const float scale       = z == 0 ? 0.125f : 1.0f;
    gemm_core<1>(xb, W, bias, C, H_, H_, scale, blockIdx.y * 128, blockIdx.x * 128);
}

__global__ __launch_bounds__(256) void gemm_out(
    const unsigned short* __restrict__ Ab, const unsigned short* __restrict__ Wo,
    const float* __restrict__ bo, float* __restrict__ out)
{
    gemm_core<0>(Ab, Wo, bo, out, H_, H_, 1.0f, blockIdx.y * 128, blockIdx.x * 128);
}

// ---------------------------------------------------------------------------
// MFMA flash attention, tr-read edition.
// Block = 256 thr (4 waves) = one (b, h, 64-q tile). K-tiles of 64.
// K: XOR-swizzled row-major (b128 frags). V and P: [*/16-col][k/4][4][16]
// subtiled row-major, consumed via ds_read_b64_tr_b16.
// bins pre-transposed+mask-folded globally: binsT[b][k][q], 255 = masked.
// ---------------------------------------------------------------------------
__global__ __launch_bounds__(256) void attn_mfma(
    const unsigned short* __restrict__ Qg, const unsigned short* __restrict__ Kg,
    const unsigned short* __restrict__ Vg, const unsigned char* __restrict__ binsT,
    const float* __restrict__ demb, const float* __restrict__ abias,
    unsigned short* __restrict__ O)
{
    const int qt = blockIdx.x;
    const int h  = blockIdx.y;
    const int b  = blockIdx.z;
    const int q0 = qt * 64;
    const int t  = threadIdx.x;
    const int lane = t & 63;
    const int wave = t >> 6;
    const int l15 = lane & 15;
    const int lhi = lane >> 4;

    __shared__ unsigned short Ks[64 * 64];       // XOR-swizzled rows
    __shared__ unsigned short Vs[64 * 64];       // [d/16][k/4][4][16] subtiled
    __shared__ unsigned short QPs[64 * 64];      // prologue: Q (swizzled); loop: P_T per wave
    __shared__ unsigned char  BsT[64 * 80];      // [k][q] bins, stride 80
    __shared__ float          dbb[256];          // demb[bin][h]+ab; [50..255] = -1e9

    const float ab = abias[h];
    for (int i = t; i < 256; i += 256)
        dbb[i] = (i < 50) ? (demb[i * NH_ + h] + ab) : -1e9f;

    // ---- stage Q (scaled by 1/8 at projection), XOR-swizzled ----
    {
        const int qr = t >> 2;
        const int d0 = (t & 3) * 16;
        const unsigned short* src = Qg + ((size_t)(b * N_ + q0 + qr)) * H_ + h * HD_ + d0;
        #pragma unroll
        for (int cc = 0; cc < 2; ++cc) {
            const uint4 v = *(const uint4*)(src + 8 * cc);
            const int idx = (qr * 64 + d0 + 8 * cc) ^ ((qr & 7) << 3);
            *(uint4*)&QPs[idx] = v;
        }
    }
    __syncthreads();

    short8 aq[2];
    {
        const int qrow = (wave << 4) + l15;
        #pragma unroll
        for (int ck = 0; ck < 2; ++ck) {
            const int kb = lhi * 8 + 32 * ck;
            const int idx = (qrow * 64 + kb) ^ ((qrow & 7) << 3);
            aq[ck] = *(const short8*)&QPs[idx];
        }
    }

    unsigned short* const Pw = &QPs[wave << 10];   // 2KB per-wave P_T region
    const unsigned trlane = (unsigned)(lhi << 8) + (unsigned)(l15 << 3);
    const unsigned paddr = (unsigned)(size_t)LPTR(Pw) + trlane;
    const unsigned vaddr = (unsigned)(size_t)LPTR(&Vs[0]) + trlane;

    float m[4], lsum[4];
    floatx4 o4[4];
    #pragma unroll
    for (int r = 0; r < 4; ++r) { m[r] = -INFINITY; lsum[r] = 0.f; }
    #pragma unroll
    for (int nd = 0; nd < 4; ++nd) o4[nd] = (floatx4)0.f;

    for (int k0 = 0; k0 < N_; k0 += 64) {
        __syncthreads();   // previous tile's reads done
        {
            const int kr = t >> 2;          // 0..63
            const int d0 = (t & 3) * 16;
            const unsigned short* ksrc = Kg + ((size_t)(b * N_ + k0 + kr)) * H_ + h * HD_ + d0;
            const unsigned short* vsrc = Vg + ((size_t)(b * N_ + k0 + kr)) * H_ + h * HD_ + d0;
            // K: row-major XOR-swizzled
            #pragma unroll
            for (int cc = 0; cc < 2; ++cc) {
                const uint4 kv = *(const uint4*)(ksrc + 8 * cc);
                const int idx = (kr * 64 + d0 + 8 * cc) ^ ((kr & 7) << 3);
                *(uint4*)&Ks[idx] = kv;
            }
            // V: subtiled [di][k4][kr][c] — two b128 stores, no per-element loop
            #pragma unroll
            for (int cc = 0; cc < 2; ++cc) {
                const uint4 vv = *(const uint4*)(vsrc + 8 * cc);
                const int idx = (t & 3) * 1024 + (kr >> 2) * 64 + (kr & 3) * 16 + 8 * cc;
                *(uint4*)&Vs[idx] = vv;
            }
            // bins tile: [k][q] stride 80
            const int qc = d0;
            *(uint4*)&BsT[kr * 80 + qc] =
                *(const uint4*)(binsT + ((size_t)(b * N_) + k0 + kr) * N_ + q0 + qc);
        }
        __syncthreads();

        // ---- S = (Q/8) K^T ----
        floatx4 s4[4];
        #pragma unroll
        for (int kn = 0; kn < 4; ++kn) {
            const int kcol = kn * 16 + l15;
            floatx4 acc = (floatx4)0.f;
            #pragma unroll
            for (int ck = 0; ck < 2; ++ck) {
                const int kb = lhi * 8 + 32 * ck;
                const int idx = (kcol * 64 + kb) ^ ((kcol & 7) << 3);
                const short8 bk = *(const short8*)&Ks[idx];
                acc = __builtin_amdgcn_mfma_f32_16x16x32_bf16(aq[ck], bk, acc, 0, 0, 0);
            }
            s4[kn] = acc;
        }

        // ---- + distance bias (mask folded: bin 255 -> -1e9) ----
        #pragma unroll
        for (int kn = 0; kn < 4; ++kn) {
            const int k = kn * 16 + l15;
            const unsigned bb = *(const unsigned*)&BsT[k * 80 + (wave << 4) + (lhi << 2)];
            s4[kn][0] += dbb[bb & 255u];
            s4[kn][1] += dbb[(bb >> 8) & 255u];
            s4[kn][2] += dbb[(bb >> 16) & 255u];
            s4[kn][3] += dbb[bb >> 24];
        }

        // ---- online softmax ----
        #pragma unroll
        for (int r = 0; r < 4; ++r) {
            float tm = fmaxf(fmaxf(s4[0][r], s4[1][r]), fmaxf(s4[2][r], s4[3][r]));
            tm = fmaxf(tm, __shfl_xor(tm, 1, 64));
            tm = fmaxf(tm, __shfl_xor(tm, 2, 64));
            tm = fmaxf(tm, __shfl_xor(tm, 4, 64));
            tm = fmaxf(tm, __shfl_xor(tm, 8, 64));
            const float mnew = fmaxf(m[r], tm);
            float ts = 0.f;
            #pragma unroll
            for (int kn = 0; kn < 4; ++kn) {
                const float p = __expf(s4[kn][r] - mnew);
                s4[kn][r] = p;
                ts += p;
            }
            ts += __shfl_xor(ts, 1, 64);
            ts += __shfl_xor(ts, 2, 64);
            ts += __shfl_xor(ts, 4, 64);
            ts += __shfl_xor(ts, 8, 64);
            const float alpha = __expf(m[r] - mnew);
            lsum[r] = lsum[r] * alpha + ts;
            m[r] = mnew;
            #pragma unroll
            for (int nd = 0; nd < 4; ++nd) o4[nd][r] *= alpha;
        }

        // ---- P_T -> LDS: lane's 4 regs are 4 consecutive q rows at fixed k ----
        #pragma unroll
        for (int kn = 0; kn < 4; ++kn) {
            short4_t pk;
            pk[0] = (short)f2bf(s4[kn][0]);
            pk[1] = (short)f2bf(s4[kn][1]);
            pk[2] = (short)f2bf(s4[kn][2]);
            pk[3] = (short)f2bf(s4[kn][3]);
            *(short4_t*)&Pw[kn * 256 + (l15 >> 2) * 64 + (l15 & 3) * 16 + lhi * 4] = pk;
        }
        asm volatile("s_waitcnt lgkmcnt(0)" ::: "memory");
        __builtin_amdgcn_sched_barrier(0);

        // ---- PV via tr-reads: issue all, drain, then 8 MFMA ----
        short4_t pa0l, pa0h, pa1l, pa1h;
        short4_t v0l[4], v0h[4], v1l[4], v1h[4];
        TRB16(pa0l, paddr, "0");    TRB16(pa0h, paddr, "128");
        TRB16(pa1l, paddr, "1024"); TRB16(pa1h, paddr, "1152");
        TRB16(v0l[0], vaddr, "0");    TRB16(v0h[0], vaddr, "128");
        TRB16(v0l[1], vaddr, "2048"); TRB16(v0h[1], vaddr, "2176");
        TRB16(v0l[2], vaddr, "4096"); TRB16(v0h[2], vaddr, "4224");
        TRB16(v0l[3], vaddr, "6144"); TRB16(v0h[3], vaddr, "6272");
        TRB16(v1l[0], vaddr, "1024"); TRB16(v1h[0], vaddr, "1152");
        TRB16(v1l[1], vaddr, "3072"); TRB16(v1h[1], vaddr, "3200");
        TRB16(v1l[2], vaddr, "5120"); TRB16(v1h[2], vaddr, "5248");
        TRB16(v1l[3], vaddr, "7168"); TRB16(v1h[3], vaddr, "7296");
        asm volatile("s_waitcnt lgkmcnt(0)" ::: "memory");
        __builtin_amdgcn_sched_barrier(0);

        const short8 ap0 = __builtin_shufflevector(pa0l, pa0h, 0, 1, 2, 3, 4, 5, 6, 7);
        const short8 ap1 = __builtin_shufflevector(pa1l, pa1h, 0, 1, 2, 3, 4, 5, 6, 7);
        #pragma unroll
        for (int nd = 0; nd < 4; ++nd) {
            const short8 bv0 = __builtin_shufflevector(v0l[nd], v0h[nd], 0, 1, 2, 3, 4, 5, 6, 7);
            o4[nd] = __builtin_amdgcn_mfma_f32_16x16x32_bf16(ap0, bv0, o4[nd], 0, 0, 0);
            const short8 bv1 = __builtin_shufflevector(v1l[nd], v1h[nd], 0, 1, 2, 3, 4, 5, 6, 7);
            o4[nd] = __builtin_amdgcn_mfma_f32_16x16x32_bf16(ap1, bv1, o4[nd], 0, 0, 0);
        }
    }

    float inv[4];
    #pragma unroll
    for (int r = 0; r < 4; ++r) inv[r] = 1.f / lsum[r];
    #pragma unroll
    for (int nd = 0; nd < 4; ++nd) {
        const int d = nd * 16 + l15;
        #pragma unroll
        for (int r = 0; r < 4; ++r) {
            const int q = q0 + (wave << 4) + lhi * 4 + r;
            O[((size_t)(b * N_ + q)) * H_ + h * HD_ + d] = f2bf(o4[nd][r] * inv[r]);
        }
    }
}

// ---------------------------------------------------------------------------
extern "C" void kernel_launch(void* const* d_in, const int* in_sizes, int n_in,
                              void* d_out, int out_size, void* d_ws, size_t ws_size,
                              hipStream_t stream)
{
    const float* x    = (const float*)d_in[0];
    const float* dist = (const float*)d_in[1];
    const int*   mask = (const int*)d_in[2];
    const float* Wq   = (const float*)d_in[3];
    const float* bq   = (const float*)d_in[4];
    const float* Wk   = (const float*)d_in[5];
    const float* bk   = (const float*)d_in[6];
    const float* Wv   = (const float*)d_in[7];
    const float* bv   = (const float*)d_in[8];
    const float* Wo   = (const float*)d_in[9];
    const float* bo   = (const float*)d_in[10];
    const float* demb = (const float*)d_in[11];
    const float* ab   = (const float*)d_in[12];
    float* out = (float*)d_out;

    const size_t mat = (size_t)B_ * N_ * H_;         // 4,194,304
    const size_t wsz = (size_t)H_ * H_;              //   262,144

    unsigned short* blob = (unsigned short*)d_ws;
    unsigned short* xb  = blob;
    unsigned short* Wqb = blob + mat;
    unsigned short* Wkb = Wqb + wsz;
    unsigned short* Wvb = Wkb + wsz;
    unsigned short* Wob = Wvb + wsz;
    unsigned short* Qb  = Wob + wsz;
    unsigned short* Kb  = Qb + mat;
    unsigned short* Vb  = Kb + mat;
    unsigned short* Ab  = Vb + mat;
    unsigned char*  binsb = (unsigned char*)(Ab + mat);

    const dim3 blk(256);

    hipLaunchKernelGGL(cvt_all, dim3(1024), blk, 0, stream, x, Wq, Wk, Wv, Wo, blob);
    hipLaunchKernelGGL(binsT_kernel, dim3(N_ / 64, N_ / 64, B_), blk, 0, stream,
                       dist, mask, binsb);

    const dim3 qgrid(H_ / 128, (B_ * N_) / 128, 3);
    hipLaunchKernelGGL(gemm_qkv, qgrid, blk, 0, stream,
                       xb, Wqb, Wkb, Wvb, bq, bk, bv, Qb, Kb, Vb);

    const dim3 agrid(N_ / 64, NH_, B_);
    hipLaunchKernelGGL(attn_mfma, agrid, blk, 0, stream,
                       Qb, Kb, Vb, binsb, demb, ab, Ab);

    const dim3 ogrid(H_ / 128, (B_ * N_) / 128, 1);
    hipLaunchKernelGGL(gemm_out, ogrid, blk, 0, stream, Ab, Wob, bo, out);
}